// Round 1
// baseline (3837.925 us; speedup 1.0000x reference)
//
#include <hip/hip_runtime.h>
#include <math.h>

#pragma clang fp contract(off)

// Problem constants (match reference)
#define PNUM 136500      // sum of f*f
#define BNUM 16
#define TOPK 5000
#define CAP 8192         // candidate capacity per image (power of 2 for bitonic)
#define NBUCK 65536
#define NTILE 79         // ceil(5000/64)

// Workspace layout (bytes)
#define OFF_HIST  ((size_t)0)                       // u32[16*65536] = 4194304
#define OFF_CUT   ((size_t)4194304)                 // u32[16]
#define OFF_GCNT  ((size_t)4194368)                 // u32[16]
#define OFF_KEYS  ((size_t)4194432)                 // u64[16*8192] = 1048576
#define OFF_SC    ((size_t)(4194432 + 1048576))     // f32[16*5000] each below
#define OFF_X1    (OFF_SC + 320000)
#define OFF_Y1    (OFF_X1 + 320000)
#define OFF_X2    (OFF_Y1 + 320000)
#define OFF_Y2    (OFF_X2 + 320000)
#define OFF_AREA  (OFF_Y2 + 320000)

__device__ __forceinline__ unsigned f2ord(float f) {
    unsigned u = __float_as_uint(f);
    return (u & 0x80000000u) ? ~u : (u | 0x80000000u);
}
__device__ __forceinline__ float ord2f(unsigned o) {
    unsigned u = (o & 0x80000000u) ? (o ^ 0x80000000u) : ~o;
    return __uint_as_float(u);
}

// K1: per-image histogram of score-order top 16 bits
__global__ void k_hist(const float* __restrict__ conf, unsigned* __restrict__ hist) {
    int p = blockIdx.x * 256 + threadIdx.x;
    int img = blockIdx.y;
    if (p >= PNUM) return;
    float s = conf[((size_t)img * PNUM + p) * 2 + 1];
    float m = (s > 0.01f) ? s : -1.0f;
    unsigned o = f2ord(m);
    atomicAdd(&hist[(size_t)img * NBUCK + (o >> 16)], 1u);
}

// K2: find cutoff bucket so that count(bucket >= cut) >= TOPK (within positive scores)
__global__ void __launch_bounds__(1024) k_cutoff(const unsigned* __restrict__ hist,
                                                 unsigned* __restrict__ cut) {
    __shared__ unsigned csum[1024];
    int img = blockIdx.x;
    int t = threadIdx.x;
    const unsigned* h = hist + (size_t)img * NBUCK;
    unsigned s = 0;
    for (int b = 0; b < 64; ++b) s += h[t * 64 + b];
    csum[t] = s;
    __syncthreads();
    if (t == 0) {
        unsigned acc = 0, before = 0;
        int c = -1;
        for (int cc = 1023; cc >= 512; --cc) {   // bucket >= 0x8000 <=> positive score
            if (acc + csum[cc] >= (unsigned)TOPK) { c = cc; before = acc; break; }
            acc += csum[cc];
        }
        unsigned cutb = 32768u;
        if (c >= 0) {
            unsigned s2 = before;
            cutb = (unsigned)c * 64u;
            for (int b = c * 64 + 63; b >= c * 64; --b) {
                s2 += h[b];
                if (s2 >= (unsigned)TOPK) { cutb = (unsigned)b; break; }
            }
        }
        cut[img] = cutb;
    }
}

// K3: gather candidate keys (ord<<32)|~p for buckets >= cutoff
__global__ void k_gather(const float* __restrict__ conf, const unsigned* __restrict__ cut,
                         unsigned* __restrict__ gcnt, unsigned long long* __restrict__ keys) {
    int p = blockIdx.x * 256 + threadIdx.x;
    int img = blockIdx.y;
    if (p >= PNUM) return;
    float s = conf[((size_t)img * PNUM + p) * 2 + 1];
    if (!(s > 0.01f)) return;                 // invalid -> never in candidates we need
    unsigned o = f2ord(s);
    if ((o >> 16) < cut[img]) return;
    unsigned pos = atomicAdd(&gcnt[img], 1u);
    if (pos < (unsigned)CAP) {
        keys[(size_t)img * CAP + pos] =
            ((unsigned long long)o << 32) | (unsigned)(~(unsigned)p);
    }
}

// K4: per-image bitonic sort (descending) of up to CAP keys; decode top-5000 boxes
__global__ void __launch_bounds__(1024) k_sortdecode(
        const unsigned long long* __restrict__ keys, const unsigned* __restrict__ gcnt,
        const float* __restrict__ loc, const float* __restrict__ pri,
        float* __restrict__ SC, float* __restrict__ X1, float* __restrict__ Y1,
        float* __restrict__ X2, float* __restrict__ Y2, float* __restrict__ AREA) {
    __shared__ unsigned long long sk[CAP];
    int img = blockIdx.x;
    int tid = threadIdx.x;
    int N = (int)min(gcnt[img], (unsigned)CAP);
    for (int i = tid; i < CAP; i += 1024)
        sk[i] = (i < N) ? keys[(size_t)img * CAP + i] : 0ull;
    __syncthreads();
    for (int k = 2; k <= CAP; k <<= 1) {
        for (int j = k >> 1; j > 0; j >>= 1) {
            for (int i = tid; i < CAP; i += 1024) {
                int p2 = i ^ j;
                if (p2 > i) {
                    unsigned long long a = sk[i], b = sk[p2];
                    bool descBlock = ((i & k) == 0);
                    bool doSwap = descBlock ? (a < b) : (a > b);
                    if (doSwap) { sk[i] = b; sk[p2] = a; }
                }
            }
            __syncthreads();
        }
    }
    // decode top TOPK
    for (int r = tid; r < TOPK; r += 1024) {
        unsigned long long key = sk[r];
        size_t o = (size_t)img * TOPK + r;
        if (key != 0ull) {
            unsigned ordv = (unsigned)(key >> 32);
            float s = ord2f(ordv);
            unsigned p = ~(unsigned)(key & 0xFFFFFFFFull);
            const float* lp = loc + ((size_t)img * PNUM + p) * 4;
            const float* pp = pri + (size_t)p * 4;
            float lx = lp[0], ly = lp[1], lw = lp[2], lh = lp[3];
            float px = pp[0], py = pp[1], pw = pp[2], ph = pp[3];
            float cx = px + (lx * 0.1f) * pw;      // priors + (loc*VAR0)*prior_wh
            float cy = py + (ly * 0.1f) * ph;
            float w = pw * expf(lw * 0.2f);        // prior_wh * exp(loc*VAR1)
            float h = ph * expf(lh * 0.2f);
            float x1 = cx - w * 0.5f;
            float y1 = cy - h * 0.5f;
            float x2 = x1 + w;
            float y2 = y1 + h;
            SC[o] = s; X1[o] = x1; Y1[o] = y1; X2[o] = x2; Y2[o] = y2;
            AREA[o] = (x2 - x1) * (y2 - y1);
        } else {
            SC[o] = -1.0f; X1[o] = 0.f; Y1[o] = 0.f; X2[o] = 0.f; Y2[o] = 0.f;
            AREA[o] = 0.f;
        }
    }
}

// K5: per-image greedy NMS (exact sequential semantics) + compaction + output write
__global__ void __launch_bounds__(1024) k_nms(
        const float* __restrict__ SC, const float* __restrict__ X1,
        const float* __restrict__ Y1, const float* __restrict__ X2,
        const float* __restrict__ Y2, const float* __restrict__ AREA,
        float* __restrict__ out) {
    __shared__ unsigned char keep[TOPK];
    __shared__ float kx1[64], ky1[64], kx2[64], ky2[64], kar[64];
    __shared__ int kcnt;
    __shared__ int wsum[16];
    int img = blockIdx.x;
    int tid = threadIdx.x;
    const float* sc = SC + (size_t)img * TOPK;
    const float* x1 = X1 + (size_t)img * TOPK;
    const float* y1 = Y1 + (size_t)img * TOPK;
    const float* x2 = X2 + (size_t)img * TOPK;
    const float* y2 = Y2 + (size_t)img * TOPK;
    const float* ar = AREA + (size_t)img * TOPK;

    for (int i = tid; i < TOPK; i += 1024) keep[i] = (sc[i] > 0.01f) ? 1 : 0;
    __syncthreads();

    for (int t = 0; t < NTILE; ++t) {
        if (tid < 64) {
            int r = t * 64 + tid;
            bool inr = (r < TOPK);
            float bx1 = 0.f, by1 = 0.f, bx2 = 0.f, by2 = 0.f, ba = 0.f;
            bool alive = false;
            if (inr) {
                bx1 = x1[r]; by1 = y1[r]; bx2 = x2[r]; by2 = y2[r]; ba = ar[r];
                alive = (keep[r] != 0);
            }
            unsigned long long m = __ballot(alive);
            for (int i = 0; i < 63; ++i) {
                if (!((m >> i) & 1ull)) continue;
                float ix1 = __shfl(bx1, i, 64);
                float iy1 = __shfl(by1, i, 64);
                float ix2 = __shfl(bx2, i, 64);
                float iy2 = __shfl(by2, i, 64);
                float ia  = __shfl(ba, i, 64);
                if (tid > i && alive) {
                    float iw = fmaxf(fminf(bx2, ix2) - fmaxf(bx1, ix1), 0.0f);
                    float ih = fmaxf(fminf(by2, iy2) - fmaxf(by1, iy1), 0.0f);
                    float inter = iw * ih;
                    float iou = inter / (ba + ia - inter);
                    if (iou > 0.3f) alive = false;
                }
                m = __ballot(alive);
            }
            if (inr) keep[r] = alive ? 1 : 0;
            int rank = __popcll(m & ((1ull << tid) - 1ull));
            if (alive) {
                kx1[rank] = bx1; ky1[rank] = by1; kx2[rank] = bx2; ky2[rank] = by2;
                kar[rank] = ba;
            }
            if (tid == 0) kcnt = (int)__popcll(m);
        }
        __syncthreads();
        int kc = kcnt;
        if (kc > 0) {
            for (int j = (t + 1) * 64 + tid; j < TOPK; j += 1024) {
                if (keep[j]) {
                    float jx1 = x1[j], jy1 = y1[j], jx2 = x2[j], jy2 = y2[j], ja = ar[j];
                    bool dead = false;
                    for (int q = 0; q < kc; ++q) {
                        float iw = fmaxf(fminf(jx2, kx2[q]) - fmaxf(jx1, kx1[q]), 0.0f);
                        float ih = fmaxf(fminf(jy2, ky2[q]) - fmaxf(jy1, ky1[q]), 0.0f);
                        float inter = iw * ih;
                        float iou = inter / (ja + kar[q] - inter);
                        if (iou > 0.3f) { dead = true; break; }
                    }
                    if (dead) keep[j] = 0;
                }
            }
        }
        __syncthreads();
    }

    // Compaction: exclusive scan of keep, write kept rows to class-1 plane
    int base = tid * 5;
    int cnt = 0;
    for (int e = 0; e < 5; ++e) {
        int idx = base + e;
        if (idx < TOPK && keep[idx]) cnt++;
    }
    int lane = tid & 63, wv = tid >> 6;
    int v = cnt;
    for (int d = 1; d < 64; d <<= 1) {
        int u = __shfl_up(v, (unsigned)d, 64);
        if (lane >= d) v += u;
    }
    if (lane == 63) wsum[wv] = v;
    __syncthreads();
    if (tid == 0) {
        int acc = 0;
        for (int w2 = 0; w2 < 16; ++w2) { int x = wsum[w2]; wsum[w2] = acc; acc += x; }
    }
    __syncthreads();
    int excl = wsum[wv] + v - cnt;
    float* op = out + (((size_t)img * 2) + 1) * TOPK * 5;
    int rnk = excl;
    for (int e = 0; e < 5; ++e) {
        int idx = base + e;
        if (idx < TOPK && keep[idx]) {
            float* row = op + (size_t)rnk * 5;
            row[0] = sc[idx];
            row[1] = x1[idx];
            row[2] = y1[idx];
            row[3] = x2[idx];
            row[4] = y2[idx];
            rnk++;
        }
    }
}

extern "C" void kernel_launch(void* const* d_in, const int* in_sizes, int n_in,
                              void* d_out, int out_size, void* d_ws, size_t ws_size,
                              hipStream_t stream) {
    (void)in_sizes; (void)n_in; (void)ws_size;
    const float* loc  = (const float*)d_in[0];   // (16, 136500, 4)
    const float* conf = (const float*)d_in[1];   // (16*136500, 2)
    const float* pri  = (const float*)d_in[2];   // (136500, 4)
    float* out = (float*)d_out;                  // (16, 2, 5000, 5)
    char* ws = (char*)d_ws;

    unsigned* hist = (unsigned*)(ws + OFF_HIST);
    unsigned* cut  = (unsigned*)(ws + OFF_CUT);
    unsigned* gcnt = (unsigned*)(ws + OFF_GCNT);
    unsigned long long* keys = (unsigned long long*)(ws + OFF_KEYS);
    float* SC   = (float*)(ws + OFF_SC);
    float* X1   = (float*)(ws + OFF_X1);
    float* Y1   = (float*)(ws + OFF_Y1);
    float* X2   = (float*)(ws + OFF_X2);
    float* Y2   = (float*)(ws + OFF_Y2);
    float* AREA = (float*)(ws + OFF_AREA);

    // zero: entire output (class-0 plane + tail rows), hist, cut, gcnt
    hipMemsetAsync(d_out, 0, (size_t)out_size * sizeof(float), stream);
    hipMemsetAsync(d_ws, 0, OFF_KEYS, stream);

    dim3 gb((PNUM + 255) / 256, BNUM);
    k_hist<<<gb, 256, 0, stream>>>(conf, hist);
    k_cutoff<<<BNUM, 1024, 0, stream>>>(hist, cut);
    k_gather<<<gb, 256, 0, stream>>>(conf, cut, gcnt, keys);
    k_sortdecode<<<BNUM, 1024, 0, stream>>>(keys, gcnt, loc, pri, SC, X1, Y1, X2, Y2, AREA);
    k_nms<<<BNUM, 1024, 0, stream>>>(SC, X1, Y1, X2, Y2, AREA, out);
}

// Round 2
// 2382.376 us; speedup vs baseline: 1.6110x; 1.6110x over previous
//
#include <hip/hip_runtime.h>
#include <math.h>

#pragma clang fp contract(off)

// Problem constants (match reference)
#define PNUM 136500      // sum of f*f
#define BNUM 16
#define TOPK 5000
#define CAP 8192         // candidate capacity per image (power of 2 for bitonic)
#define NBUCK 65536
#define NWORDS 79        // ceil(5000/64)
#define ROWSTRIDE 80     // u64 words per mask row (padded)

// Workspace layout (bytes)
#define OFF_HIST  ((size_t)0)                       // u32[16*65536] = 4194304
#define OFF_CUT   ((size_t)4194304)                 // u32[16]
#define OFF_GCNT  ((size_t)4194368)                 // u32[16]
#define OFF_KEYS  ((size_t)4194432)                 // u64[16*8192] = 1048576
#define OFF_SC    ((size_t)(4194432 + 1048576))     // f32[16*5000] each below
#define OFF_X1    (OFF_SC + 320000)
#define OFF_Y1    (OFF_X1 + 320000)
#define OFF_X2    (OFF_Y1 + 320000)
#define OFF_Y2    (OFF_X2 + 320000)
#define OFF_AREA  (OFF_Y2 + 320000)
#define OFF_MASK  ((size_t)7163904)                 // aligned past OFF_AREA+320000
#define MASK_PER_IMG ((size_t)TOPK * ROWSTRIDE * 8) // 3,200,000 B

__device__ __forceinline__ unsigned f2ord(float f) {
    unsigned u = __float_as_uint(f);
    return (u & 0x80000000u) ? ~u : (u | 0x80000000u);
}
__device__ __forceinline__ float ord2f(unsigned o) {
    unsigned u = (o & 0x80000000u) ? (o ^ 0x80000000u) : ~o;
    return __uint_as_float(u);
}

// K1: per-image histogram of score-order top 16 bits
__global__ void k_hist(const float* __restrict__ conf, unsigned* __restrict__ hist) {
    int p = blockIdx.x * 256 + threadIdx.x;
    int img = blockIdx.y;
    if (p >= PNUM) return;
    float s = conf[((size_t)img * PNUM + p) * 2 + 1];
    float m = (s > 0.01f) ? s : -1.0f;
    unsigned o = f2ord(m);
    atomicAdd(&hist[(size_t)img * NBUCK + (o >> 16)], 1u);
}

// K2: find cutoff bucket so that count(bucket >= cut) >= TOPK (within positive scores)
__global__ void __launch_bounds__(1024) k_cutoff(const unsigned* __restrict__ hist,
                                                 unsigned* __restrict__ cut) {
    __shared__ unsigned csum[1024];
    int img = blockIdx.x;
    int t = threadIdx.x;
    const unsigned* h = hist + (size_t)img * NBUCK;
    unsigned s = 0;
    for (int b = 0; b < 64; ++b) s += h[t * 64 + b];
    csum[t] = s;
    __syncthreads();
    if (t == 0) {
        unsigned acc = 0, before = 0;
        int c = -1;
        for (int cc = 1023; cc >= 512; --cc) {   // bucket >= 0x8000 <=> positive score
            if (acc + csum[cc] >= (unsigned)TOPK) { c = cc; before = acc; break; }
            acc += csum[cc];
        }
        unsigned cutb = 32768u;
        if (c >= 0) {
            unsigned s2 = before;
            cutb = (unsigned)c * 64u;
            for (int b = c * 64 + 63; b >= c * 64; --b) {
                s2 += h[b];
                if (s2 >= (unsigned)TOPK) { cutb = (unsigned)b; break; }
            }
        }
        cut[img] = cutb;
    }
}

// K3: gather candidate keys (ord<<32)|~p for buckets >= cutoff
__global__ void k_gather(const float* __restrict__ conf, const unsigned* __restrict__ cut,
                         unsigned* __restrict__ gcnt, unsigned long long* __restrict__ keys) {
    int p = blockIdx.x * 256 + threadIdx.x;
    int img = blockIdx.y;
    if (p >= PNUM) return;
    float s = conf[((size_t)img * PNUM + p) * 2 + 1];
    if (!(s > 0.01f)) return;
    unsigned o = f2ord(s);
    if ((o >> 16) < cut[img]) return;
    unsigned pos = atomicAdd(&gcnt[img], 1u);
    if (pos < (unsigned)CAP) {
        keys[(size_t)img * CAP + pos] =
            ((unsigned long long)o << 32) | (unsigned)(~(unsigned)p);
    }
}

// K4: per-image bitonic sort (descending) of up to CAP keys; decode top-5000 boxes
__global__ void __launch_bounds__(1024) k_sortdecode(
        const unsigned long long* __restrict__ keys, const unsigned* __restrict__ gcnt,
        const float* __restrict__ loc, const float* __restrict__ pri,
        float* __restrict__ SC, float* __restrict__ X1, float* __restrict__ Y1,
        float* __restrict__ X2, float* __restrict__ Y2, float* __restrict__ AREA) {
    __shared__ unsigned long long sk[CAP];
    int img = blockIdx.x;
    int tid = threadIdx.x;
    int N = (int)min(gcnt[img], (unsigned)CAP);
    for (int i = tid; i < CAP; i += 1024)
        sk[i] = (i < N) ? keys[(size_t)img * CAP + i] : 0ull;
    __syncthreads();
    for (int k = 2; k <= CAP; k <<= 1) {
        for (int j = k >> 1; j > 0; j >>= 1) {
            for (int i = tid; i < CAP; i += 1024) {
                int p2 = i ^ j;
                if (p2 > i) {
                    unsigned long long a = sk[i], b = sk[p2];
                    bool descBlock = ((i & k) == 0);
                    bool doSwap = descBlock ? (a < b) : (a > b);
                    if (doSwap) { sk[i] = b; sk[p2] = a; }
                }
            }
            __syncthreads();
        }
    }
    for (int r = tid; r < TOPK; r += 1024) {
        unsigned long long key = sk[r];
        size_t o = (size_t)img * TOPK + r;
        if (key != 0ull) {
            unsigned ordv = (unsigned)(key >> 32);
            float s = ord2f(ordv);
            unsigned p = ~(unsigned)(key & 0xFFFFFFFFull);
            const float* lp = loc + ((size_t)img * PNUM + p) * 4;
            const float* pp = pri + (size_t)p * 4;
            float lx = lp[0], ly = lp[1], lw = lp[2], lh = lp[3];
            float px = pp[0], py = pp[1], pw = pp[2], ph = pp[3];
            float cx = px + (lx * 0.1f) * pw;
            float cy = py + (ly * 0.1f) * ph;
            float w = pw * expf(lw * 0.2f);
            float h = ph * expf(lh * 0.2f);
            float x1 = cx - w * 0.5f;
            float y1 = cy - h * 0.5f;
            float x2 = x1 + w;
            float y2 = y1 + h;
            SC[o] = s; X1[o] = x1; Y1[o] = y1; X2[o] = x2; Y2[o] = y2;
            AREA[o] = (x2 - x1) * (y2 - y1);
        } else {
            SC[o] = -1.0f; X1[o] = 0.f; Y1[o] = 0.f; X2[o] = 0.f; Y2[o] = 0.f;
            AREA[o] = 0.f;
        }
    }
}

// K5a: suppression-mask matrix. mask[g][i][cb] bit jj = 1 iff row i (if valid)
// suppresses column j = cb*64+jj (j > i, iou > 0.3). Bit-exact reference math.
__global__ void __launch_bounds__(256) k_mask(
        const float* __restrict__ SC, const float* __restrict__ X1,
        const float* __restrict__ Y1, const float* __restrict__ X2,
        const float* __restrict__ Y2, const float* __restrict__ AREA,
        unsigned long long* __restrict__ mask, int img0) {
    __shared__ float cx1[64], cy1[64], cx2[64], cy2[64], car[64];
    int g = blockIdx.z;
    int img = img0 + g;
    int cb = blockIdx.y;
    int i = blockIdx.x * 256 + threadIdx.x;
    int t = threadIdx.x;
    size_t ib = (size_t)img * TOPK;
    if (t < 64) {
        int j = cb * 64 + t;
        if (j < TOPK) {
            cx1[t] = X1[ib + j]; cy1[t] = Y1[ib + j];
            cx2[t] = X2[ib + j]; cy2[t] = Y2[ib + j];
            car[t] = AREA[ib + j];
        } else {
            cx1[t] = 0.f; cy1[t] = 0.f; cx2[t] = 0.f; cy2[t] = 0.f; car[t] = 0.f;
        }
    }
    __syncthreads();
    if (i >= TOPK) return;
    unsigned long long w = 0;
    if (cb * 64 + 63 > i) {                     // some column j > i exists
        float vi = SC[ib + i];
        if (vi > 0.01f) {                        // suppressor must be valid
            float rx1 = X1[ib + i], ry1 = Y1[ib + i];
            float rx2 = X2[ib + i], ry2 = Y2[ib + i];
            float ra = AREA[ib + i];
            #pragma unroll 8
            for (int jj = 0; jj < 64; ++jj) {
                int j = cb * 64 + jj;
                if (j <= i || j >= TOPK) continue;
                float iw = fmaxf(fminf(rx2, cx2[jj]) - fmaxf(rx1, cx1[jj]), 0.0f);
                float ih = fmaxf(fminf(ry2, cy2[jj]) - fmaxf(ry1, cy1[jj]), 0.0f);
                float inter = iw * ih;
                float iou = inter / (car[jj] + ra - inter);  // (area_j + area_i) - inter
                if (iou > 0.3f) w |= (1ull << jj);
            }
        }
    }
    mask[((size_t)g * TOPK + i) * ROWSTRIDE + cb] = w;
}

// K5b: serial greedy scan over precomputed masks (one wave per image) + compaction.
__global__ void __launch_bounds__(64) k_scan(
        const float* __restrict__ SC, const float* __restrict__ X1,
        const float* __restrict__ Y1, const float* __restrict__ X2,
        const float* __restrict__ Y2,
        const unsigned long long* __restrict__ mask, float* __restrict__ out, int img0) {
    __shared__ unsigned long long keepw[80];
    __shared__ unsigned pfx[80];
    int g = blockIdx.x;
    int img = img0 + g;
    int l = threadIdx.x;
    size_t ib = (size_t)img * TOPK;
    const float* sc = SC + ib;

    // removed bitmask in registers: lane l owns word l (rem0) and word 64+l (rem1, l<15)
    unsigned long long rem0 = ~0ull, rem1 = ~0ull;
    for (int w = 0; w < 79; ++w) {
        int row = w * 64 + l;
        bool valid = (row < TOPK) && (sc[row] > 0.01f);
        unsigned long long b = __ballot(valid);
        unsigned long long remw = ~b;
        if (w < 64) { if (l == w) rem0 = remw; }
        else        { if (l == w - 64) rem1 = remw; }
    }

    const unsigned long long* mrow = mask + (size_t)g * TOPK * ROWSTRIDE;
    unsigned long long m0 = mrow[l];
    unsigned long long m1 = (l < 15) ? mrow[64 + l] : 0ull;
    for (int i = 0; i < TOPK; ++i) {
        unsigned long long n0 = 0ull, n1 = 0ull;
        if (i + 1 < TOPK) {
            const unsigned long long* nr = mrow + (size_t)(i + 1) * ROWSTRIDE;
            n0 = nr[l];
            n1 = (l < 15) ? nr[64 + l] : 0ull;
        }
        int w = i >> 6, b = i & 63;
        unsigned long long cur = (w < 64) ? __shfl(rem0, w, 64)
                                          : __shfl(rem1, w - 64, 64);
        bool alive = !((cur >> b) & 1ull);
        if (alive) { rem0 |= m0; rem1 |= m1; }
        m0 = n0; m1 = n1;
    }

    keepw[l] = ~rem0;
    if (l < 15) keepw[64 + l] = ~rem1;
    if (l == 0) keepw[79] = 0ull;
    __syncthreads();
    if (l == 0) {
        unsigned acc = 0;
        for (int w = 0; w < 79; ++w) { pfx[w] = acc; acc += (unsigned)__popcll(keepw[w]); }
    }
    __syncthreads();

    const float* x1 = X1 + ib; const float* y1 = Y1 + ib;
    const float* x2 = X2 + ib; const float* y2 = Y2 + ib;
    float* op = out + (((size_t)img * 2) + 1) * TOPK * 5;
    for (int w = 0; w < 79; ++w) {
        unsigned long long kw = keepw[w];
        if (!kw) continue;
        int row = w * 64 + l;
        if ((kw >> l) & 1ull) {
            int rank = (int)pfx[w] + (int)__popcll(kw & ((1ull << l) - 1ull));
            float* r = op + (size_t)rank * 5;
            r[0] = sc[row]; r[1] = x1[row]; r[2] = y1[row];
            r[3] = x2[row]; r[4] = y2[row];
        }
    }
}

extern "C" void kernel_launch(void* const* d_in, const int* in_sizes, int n_in,
                              void* d_out, int out_size, void* d_ws, size_t ws_size,
                              hipStream_t stream) {
    (void)in_sizes; (void)n_in;
    const float* loc  = (const float*)d_in[0];   // (16, 136500, 4)
    const float* conf = (const float*)d_in[1];   // (16*136500, 2)
    const float* pri  = (const float*)d_in[2];   // (136500, 4)
    float* out = (float*)d_out;                  // (16, 2, 5000, 5)
    char* ws = (char*)d_ws;

    unsigned* hist = (unsigned*)(ws + OFF_HIST);
    unsigned* cut  = (unsigned*)(ws + OFF_CUT);
    unsigned* gcnt = (unsigned*)(ws + OFF_GCNT);
    unsigned long long* keys = (unsigned long long*)(ws + OFF_KEYS);
    float* SC   = (float*)(ws + OFF_SC);
    float* X1   = (float*)(ws + OFF_X1);
    float* Y1   = (float*)(ws + OFF_Y1);
    float* X2   = (float*)(ws + OFF_X2);
    float* Y2   = (float*)(ws + OFF_Y2);
    float* AREA = (float*)(ws + OFF_AREA);
    unsigned long long* mask = (unsigned long long*)(ws + OFF_MASK);

    hipMemsetAsync(d_out, 0, (size_t)out_size * sizeof(float), stream);
    hipMemsetAsync(d_ws, 0, OFF_KEYS, stream);

    dim3 gb((PNUM + 255) / 256, BNUM);
    k_hist<<<gb, 256, 0, stream>>>(conf, hist);
    k_cutoff<<<BNUM, 1024, 0, stream>>>(hist, cut);
    k_gather<<<gb, 256, 0, stream>>>(conf, cut, gcnt, keys);
    k_sortdecode<<<BNUM, 1024, 0, stream>>>(keys, gcnt, loc, pri, SC, X1, Y1, X2, Y2, AREA);

    // NMS: mask matrix (parallel) + serial bit-scan, in image passes sized by ws
    size_t avail = (ws_size > OFF_MASK) ? ws_size - OFF_MASK : 0;
    int gmax = (int)(avail / MASK_PER_IMG);
    if (gmax < 1) gmax = 1;
    if (gmax > BNUM) gmax = BNUM;
    for (int i0 = 0; i0 < BNUM; i0 += gmax) {
        int G = (BNUM - i0 < gmax) ? (BNUM - i0) : gmax;
        dim3 mg((TOPK + 255) / 256, NWORDS, G);
        k_mask<<<mg, 256, 0, stream>>>(SC, X1, Y1, X2, Y2, AREA, mask, i0);
        k_scan<<<G, 64, 0, stream>>>(SC, X1, Y1, X2, Y2, mask, out, i0);
    }
}

// Round 3
// 1436.242 us; speedup vs baseline: 2.6722x; 1.6588x over previous
//
#include <hip/hip_runtime.h>
#include <math.h>

#pragma clang fp contract(off)

// Problem constants (match reference)
#define PNUM 136500      // sum of f*f
#define BNUM 16
#define TOPK 5000
#define CAP 8192         // candidate capacity per image (power of 2 for bitonic)
#define NBUCK 65536
#define NWORDS 79        // ceil(5000/64)
#define TRI_WORDS 202240 // per-image triangular mask words: 64 * (79+78+...+1)
#define MASK_PER_IMG ((size_t)TRI_WORDS * 8)   // 1,617,920 B

// Workspace layout (bytes)
#define OFF_HIST  ((size_t)0)                       // u32[16*65536] = 4194304
#define OFF_CUT   ((size_t)4194304)                 // u32[16]
#define OFF_GCNT  ((size_t)4194368)                 // u32[16]
#define OFF_KEYS  ((size_t)4194432)                 // u64[16*8192] = 1048576
#define OFF_SC    ((size_t)(4194432 + 1048576))     // f32[16*5000] each below
#define OFF_X1    (OFF_SC + 320000)
#define OFF_Y1    (OFF_X1 + 320000)
#define OFF_X2    (OFF_Y1 + 320000)
#define OFF_Y2    (OFF_X2 + 320000)
#define OFF_AREA  (OFF_Y2 + 320000)
#define OFF_MASK  ((size_t)7163904)

__device__ __forceinline__ unsigned f2ord(float f) {
    unsigned u = __float_as_uint(f);
    return (u & 0x80000000u) ? ~u : (u | 0x80000000u);
}
__device__ __forceinline__ float ord2f(unsigned o) {
    unsigned u = (o & 0x80000000u) ? (o ^ 0x80000000u) : ~o;
    return __uint_as_float(u);
}
// word-offset of 64-row block t's slab within an image's triangular mask
__device__ __forceinline__ int tri_base(int t) {
    return 64 * (79 * t - ((t * (t - 1)) >> 1));
}

// K1: per-image histogram of score-order top 16 bits
__global__ void k_hist(const float* __restrict__ conf, unsigned* __restrict__ hist) {
    int p = blockIdx.x * 256 + threadIdx.x;
    int img = blockIdx.y;
    if (p >= PNUM) return;
    float s = conf[((size_t)img * PNUM + p) * 2 + 1];
    float m = (s > 0.01f) ? s : -1.0f;
    unsigned o = f2ord(m);
    atomicAdd(&hist[(size_t)img * NBUCK + (o >> 16)], 1u);
}

// K2: find cutoff bucket so that count(bucket >= cut) >= TOPK (within positive scores)
__global__ void __launch_bounds__(1024) k_cutoff(const unsigned* __restrict__ hist,
                                                 unsigned* __restrict__ cut) {
    __shared__ unsigned csum[1024];
    int img = blockIdx.x;
    int t = threadIdx.x;
    const unsigned* h = hist + (size_t)img * NBUCK;
    unsigned s = 0;
    for (int b = 0; b < 64; ++b) s += h[t * 64 + b];
    csum[t] = s;
    __syncthreads();
    if (t == 0) {
        unsigned acc = 0, before = 0;
        int c = -1;
        for (int cc = 1023; cc >= 512; --cc) {
            if (acc + csum[cc] >= (unsigned)TOPK) { c = cc; before = acc; break; }
            acc += csum[cc];
        }
        unsigned cutb = 32768u;
        if (c >= 0) {
            unsigned s2 = before;
            cutb = (unsigned)c * 64u;
            for (int b = c * 64 + 63; b >= c * 64; --b) {
                s2 += h[b];
                if (s2 >= (unsigned)TOPK) { cutb = (unsigned)b; break; }
            }
        }
        cut[img] = cutb;
    }
}

// K3: gather candidate keys (ord<<32)|~p for buckets >= cutoff
__global__ void k_gather(const float* __restrict__ conf, const unsigned* __restrict__ cut,
                         unsigned* __restrict__ gcnt, unsigned long long* __restrict__ keys) {
    int p = blockIdx.x * 256 + threadIdx.x;
    int img = blockIdx.y;
    if (p >= PNUM) return;
    float s = conf[((size_t)img * PNUM + p) * 2 + 1];
    if (!(s > 0.01f)) return;
    unsigned o = f2ord(s);
    if ((o >> 16) < cut[img]) return;
    unsigned pos = atomicAdd(&gcnt[img], 1u);
    if (pos < (unsigned)CAP) {
        keys[(size_t)img * CAP + pos] =
            ((unsigned long long)o << 32) | (unsigned)(~(unsigned)p);
    }
}

// K4: per-image bitonic sort (descending) of up to CAP keys; decode top-5000 boxes
__global__ void __launch_bounds__(1024) k_sortdecode(
        const unsigned long long* __restrict__ keys, const unsigned* __restrict__ gcnt,
        const float* __restrict__ loc, const float* __restrict__ pri,
        float* __restrict__ SC, float* __restrict__ X1, float* __restrict__ Y1,
        float* __restrict__ X2, float* __restrict__ Y2, float* __restrict__ AREA) {
    __shared__ unsigned long long sk[CAP];
    int img = blockIdx.x;
    int tid = threadIdx.x;
    int N = (int)min(gcnt[img], (unsigned)CAP);
    for (int i = tid; i < CAP; i += 1024)
        sk[i] = (i < N) ? keys[(size_t)img * CAP + i] : 0ull;
    __syncthreads();
    for (int k = 2; k <= CAP; k <<= 1) {
        for (int j = k >> 1; j > 0; j >>= 1) {
            for (int i = tid; i < CAP; i += 1024) {
                int p2 = i ^ j;
                if (p2 > i) {
                    unsigned long long a = sk[i], b = sk[p2];
                    bool descBlock = ((i & k) == 0);
                    bool doSwap = descBlock ? (a < b) : (a > b);
                    if (doSwap) { sk[i] = b; sk[p2] = a; }
                }
            }
            __syncthreads();
        }
    }
    for (int r = tid; r < TOPK; r += 1024) {
        unsigned long long key = sk[r];
        size_t o = (size_t)img * TOPK + r;
        if (key != 0ull) {
            unsigned ordv = (unsigned)(key >> 32);
            float s = ord2f(ordv);
            unsigned p = ~(unsigned)(key & 0xFFFFFFFFull);
            const float* lp = loc + ((size_t)img * PNUM + p) * 4;
            const float* pp = pri + (size_t)p * 4;
            float lx = lp[0], ly = lp[1], lw = lp[2], lh = lp[3];
            float px = pp[0], py = pp[1], pw = pp[2], ph = pp[3];
            float cx = px + (lx * 0.1f) * pw;
            float cy = py + (ly * 0.1f) * ph;
            float w = pw * expf(lw * 0.2f);
            float h = ph * expf(lh * 0.2f);
            float x1 = cx - w * 0.5f;
            float y1 = cy - h * 0.5f;
            float x2 = x1 + w;
            float y2 = y1 + h;
            SC[o] = s; X1[o] = x1; Y1[o] = y1; X2[o] = x2; Y2[o] = y2;
            AREA[o] = (x2 - x1) * (y2 - y1);
        } else {
            SC[o] = -1.0f; X1[o] = 0.f; Y1[o] = 0.f; X2[o] = 0.f; Y2[o] = 0.f;
            AREA[o] = 0.f;
        }
    }
}

// K5a: triangular suppression-mask. Row i stores words w in [i>>6, 79) at
// g*TRI_WORDS + tri_base(t) + (i&63)*(79-t) + (w-t). Bit jj of word w = 1 iff
// row i (valid) suppresses j = w*64+jj (j > i, iou > 0.3). Bit-exact ref math.
__global__ void __launch_bounds__(256) k_mask(
        const float* __restrict__ SC, const float* __restrict__ X1,
        const float* __restrict__ Y1, const float* __restrict__ X2,
        const float* __restrict__ Y2, const float* __restrict__ AREA,
        unsigned long long* __restrict__ mask, int img0) {
    int g = blockIdx.z;
    int cb = blockIdx.y;
    int bx = blockIdx.x;
    if ((cb + 1) * 64 <= bx * 256) return;   // whole block strictly sub-diagonal
    __shared__ float cx1[64], cy1[64], cx2[64], cy2[64], car[64];
    int img = img0 + g;
    int i = bx * 256 + threadIdx.x;
    int t = threadIdx.x;
    size_t ib = (size_t)img * TOPK;
    if (t < 64) {
        int j = cb * 64 + t;
        if (j < TOPK) {
            cx1[t] = X1[ib + j]; cy1[t] = Y1[ib + j];
            cx2[t] = X2[ib + j]; cy2[t] = Y2[ib + j];
            car[t] = AREA[ib + j];
        } else {
            cx1[t] = 0.f; cy1[t] = 0.f; cx2[t] = 0.f; cy2[t] = 0.f; car[t] = 0.f;
        }
    }
    __syncthreads();
    if (i >= TOPK) return;
    int ti = i >> 6;
    if (cb < ti) return;                     // sub-diagonal word: not stored
    unsigned long long w = 0;
    float vi = SC[ib + i];
    if (vi > 0.01f) {
        float rx1 = X1[ib + i], ry1 = Y1[ib + i];
        float rx2 = X2[ib + i], ry2 = Y2[ib + i];
        float ra = AREA[ib + i];
        #pragma unroll 8
        for (int jj = 0; jj < 64; ++jj) {
            int j = cb * 64 + jj;
            if (j <= i || j >= TOPK) continue;
            float iw = fmaxf(fminf(rx2, cx2[jj]) - fmaxf(rx1, cx1[jj]), 0.0f);
            float ih = fmaxf(fminf(ry2, cy2[jj]) - fmaxf(ry1, cy1[jj]), 0.0f);
            float inter = iw * ih;
            float iou = inter / (car[jj] + ra - inter);  // (area_j + area_i) - inter
            if (iou > 0.3f) w |= (1ull << jj);
        }
    }
    int s = NWORDS - ti;
    mask[(size_t)g * TRI_WORDS + (size_t)tri_base(ti)
         + (size_t)(i & 63) * s + (cb - ti)] = w;
}

// K5b: blocked greedy scan. Wave 0: register-resolve 64 rows/block + OR-apply
// surviving rows' future masks into lane-owned rem words. Waves 1-3: LDS
// double-buffer prefetch of the next block's mask slab. One block per image.
__global__ void __launch_bounds__(256) k_scan2(
        const float* __restrict__ SC, const float* __restrict__ X1,
        const float* __restrict__ Y1, const float* __restrict__ X2,
        const float* __restrict__ Y2,
        const unsigned long long* __restrict__ mask, float* __restrict__ out, int img0) {
    __shared__ unsigned long long buf0[64 * NWORDS];
    __shared__ unsigned long long buf1[64 * NWORDS];
    __shared__ unsigned long long keepw[80];
    __shared__ unsigned pfx[80];
    int g = blockIdx.x;
    int img = img0 + g;
    int tid = threadIdx.x;
    int l = tid & 63;
    int wid = tid >> 6;
    size_t ib = (size_t)img * TOPK;
    const float* sc = SC + ib;
    const unsigned long long* mimg = mask + (size_t)g * TRI_WORDS;

    // lane l of wave 0 owns removed-words l (rem0) and 64+l (rem1, l<15)
    unsigned long long rem0 = ~0ull, rem1 = ~0ull;
    if (wid == 0) {
        for (int w = 0; w < NWORDS; ++w) {
            int row = w * 64 + l;
            bool valid = (row < TOPK) && (sc[row] > 0.01f);
            unsigned long long b = __ballot(valid);
            unsigned long long remw = ~b;
            if (l == w) rem0 = remw;
            if (l == w - 64) rem1 = remw;
        }
    } else {
        for (int idx = tid - 64; idx < 64 * NWORDS; idx += 192)
            buf0[idx] = mimg[idx];
    }
    __syncthreads();

    for (int t = 0; t < NWORDS; ++t) {
        const unsigned long long* cur = (t & 1) ? buf1 : buf0;
        int s = NWORDS - t;
        if (wid != 0) {
            if (t + 1 < NWORDS) {
                unsigned long long* nxt = (t & 1) ? buf0 : buf1;
                const unsigned long long* src = mimg + tri_base(t + 1);
                int cnt = 64 * (s - 1);
                for (int idx = tid - 64; idx < cnt; idx += 192) nxt[idx] = src[idx];
            }
        } else {
            // (a) intra-block resolve: pure-register serial chain
            unsigned long long diag[64];
            #pragma unroll
            for (int r = 0; r < 64; ++r) diag[r] = cur[r * s];   // broadcast reads
            unsigned long long remT = (t < 64) ? __shfl(rem0, t, 64)
                                               : __shfl(rem1, t - 64, 64);
            #pragma unroll
            for (int b = 0; b < 64; ++b)
                if (!((remT >> b) & 1ull)) remT |= diag[b];
            unsigned long long alive = ~remT;
            // (b) apply surviving rows' future-mask words to owned rem words
            bool p0 = (l >= t);
            int o0 = p0 ? (l - t) : 0;
            int w1 = 64 + l;
            bool p1 = (l < 15) && (w1 >= t);
            int o1 = p1 ? (w1 - t) : 0;
            #pragma unroll
            for (int b = 0; b < 64; ++b) {
                if ((alive >> b) & 1ull) {
                    unsigned long long v0 = cur[b * s + o0];
                    unsigned long long v1 = cur[b * s + o1];
                    if (p0) rem0 |= v0;     // includes w==t owner: rebuilds remT_final
                    if (p1) rem1 |= v1;
                }
            }
        }
        __syncthreads();
    }

    if (wid == 0) {
        keepw[l] = ~rem0;
        if (l < 15) keepw[64 + l] = ~rem1;
        if (l == 0) keepw[79] = 0ull;
    }
    __syncthreads();
    if (tid == 0) {
        unsigned acc = 0;
        for (int w = 0; w < NWORDS; ++w) { pfx[w] = acc; acc += (unsigned)__popcll(keepw[w]); }
    }
    __syncthreads();

    const float* x1 = X1 + ib; const float* y1 = Y1 + ib;
    const float* x2 = X2 + ib; const float* y2 = Y2 + ib;
    float* op = out + (((size_t)img * 2) + 1) * TOPK * 5;
    for (int w = wid; w < NWORDS; w += 4) {
        unsigned long long kw = keepw[w];
        if (!kw) continue;
        int row = w * 64 + l;
        if ((kw >> l) & 1ull) {
            int rank = (int)pfx[w] + (int)__popcll(kw & ((1ull << l) - 1ull));
            float* r = op + (size_t)rank * 5;
            r[0] = sc[row]; r[1] = x1[row]; r[2] = y1[row];
            r[3] = x2[row]; r[4] = y2[row];
        }
    }
}

extern "C" void kernel_launch(void* const* d_in, const int* in_sizes, int n_in,
                              void* d_out, int out_size, void* d_ws, size_t ws_size,
                              hipStream_t stream) {
    (void)in_sizes; (void)n_in;
    const float* loc  = (const float*)d_in[0];   // (16, 136500, 4)
    const float* conf = (const float*)d_in[1];   // (16*136500, 2)
    const float* pri  = (const float*)d_in[2];   // (136500, 4)
    float* out = (float*)d_out;                  // (16, 2, 5000, 5)
    char* ws = (char*)d_ws;

    unsigned* hist = (unsigned*)(ws + OFF_HIST);
    unsigned* cut  = (unsigned*)(ws + OFF_CUT);
    unsigned* gcnt = (unsigned*)(ws + OFF_GCNT);
    unsigned long long* keys = (unsigned long long*)(ws + OFF_KEYS);
    float* SC   = (float*)(ws + OFF_SC);
    float* X1   = (float*)(ws + OFF_X1);
    float* Y1   = (float*)(ws + OFF_Y1);
    float* X2   = (float*)(ws + OFF_X2);
    float* Y2   = (float*)(ws + OFF_Y2);
    float* AREA = (float*)(ws + OFF_AREA);
    unsigned long long* mask = (unsigned long long*)(ws + OFF_MASK);

    hipMemsetAsync(d_out, 0, (size_t)out_size * sizeof(float), stream);
    hipMemsetAsync(d_ws, 0, OFF_KEYS, stream);

    dim3 gb((PNUM + 255) / 256, BNUM);
    k_hist<<<gb, 256, 0, stream>>>(conf, hist);
    k_cutoff<<<BNUM, 1024, 0, stream>>>(hist, cut);
    k_gather<<<gb, 256, 0, stream>>>(conf, cut, gcnt, keys);
    k_sortdecode<<<BNUM, 1024, 0, stream>>>(keys, gcnt, loc, pri, SC, X1, Y1, X2, Y2, AREA);

    // NMS: triangular mask matrix + blocked bit-scan, in image passes sized by ws
    size_t avail = (ws_size > OFF_MASK) ? ws_size - OFF_MASK : 0;
    int gmax = (int)(avail / MASK_PER_IMG);
    if (gmax < 1) gmax = 1;
    if (gmax > BNUM) gmax = BNUM;
    for (int i0 = 0; i0 < BNUM; i0 += gmax) {
        int G = (BNUM - i0 < gmax) ? (BNUM - i0) : gmax;
        dim3 mg((TOPK + 255) / 256, NWORDS, G);
        k_mask<<<mg, 256, 0, stream>>>(SC, X1, Y1, X2, Y2, AREA, mask, i0);
        k_scan2<<<G, 256, 0, stream>>>(SC, X1, Y1, X2, Y2, mask, out, i0);
    }
}